// Round 11
// baseline (228.164 us; speedup 1.0000x reference)
//
#include <hip/hip_runtime.h>
#include <hip/hip_fp8.h>

#define M_DIM 16384
#define N_DIM 4096
#define K_DIM 2048
#define NSB   (K_DIM / 64)     // 32 k-sub-blocks per 32-row block
#define NPAIR (K_DIM / 128)    // 16 pairs of K-64 tiles

typedef float floatx16 __attribute__((ext_vector_type(16)));
typedef int   intx4    __attribute__((ext_vector_type(4)));
typedef int   intx8    __attribute__((ext_vector_type(8)));

__device__ __forceinline__ unsigned char f32_to_fp8(float v) {
    __hip_fp8_e4m3 t(v);
    return t.__x;
}

__device__ __forceinline__ float fp8_roundtrip(float v) {
    __hip_fp8_e4m3 t(v);
    return (float)t;
}

// async global->LDS, 16B per lane. LDS dest is wave-uniform base + lane*16.
__device__ __forceinline__ void async16(const void* g, void* l) {
    __builtin_amdgcn_global_load_lds((__attribute__((address_space(1))) void*)g,
                                     (__attribute__((address_space(3))) void*)l,
                                     16, 0, 0);
}

// read a lane-linear 32B fragment: two 16B halves 1024B apart (zero-conflict)
__device__ __forceinline__ intx8 ld8(const unsigned char* p) {
    intx4 lo = *(const intx4*)(p);
    intx4 hi = *(const intx4*)(p + 1024);
    return __builtin_shufflevector(lo, hi, 0, 1, 2, 3, 4, 5, 6, 7);
}

// ---- quantize + pack into 32x32x64-MFMA fragment order (unchanged) ----
// Sub-block = 32 rows x 64 k = 2048 B. qX[rb][kt][2048], rb = m>>5, kt = k>>6.
// Lane l (r = l&31, h = l>>5) owns k-window kt*64 + h*32 .. +31, stored as
// bytes 0-15 at l*16 and bytes 16-31 at 1024 + l*16. Staging is identity
// (lane-linear 16B), fragment reads are lane-linear ds_read_b128 -> zero bank
// conflicts. A and B share this map, so any hardware-internal k permutation
// cancels in the MFMA dot product.
__global__ void quant_pack_kernel(const float* __restrict__ in,
                                  unsigned char* __restrict__ out,
                                  const float* __restrict__ sp) {
    const int p = blockIdx.x * blockDim.x + threadIdx.x;  // one 16B packed chunk
    const float s = sp ? *sp : 1.0f;
    const int c    = p & 127;            // chunk within sub-block
    const int sb   = p >> 7;
    const int kt   = sb & (NSB - 1);
    const int rb   = sb >> 5;            // log2(NSB) = 5
    const int half = c >> 6;
    const int l    = c & 63;
    const size_t m = (size_t)rb * 32 + (l & 31);
    const int   k0 = kt * 64 + (l >> 5) * 32 + half * 16;
    const float* src = in + m * K_DIM + k0;
    float f[16];
    *(float4*)(f)      = *(const float4*)(src);
    *(float4*)(f + 4)  = *(const float4*)(src + 4);
    *(float4*)(f + 8)  = *(const float4*)(src + 8);
    *(float4*)(f + 12) = *(const float4*)(src + 12);
    unsigned long long lo = 0, hi = 0;
#pragma unroll
    for (int j = 0; j < 8; ++j) {
        float v0 = fminf(fmaxf(f[j] * s, -0.5f), 0.5f);
        float v1 = fminf(fmaxf(f[j + 8] * s, -0.5f), 0.5f);
        lo |= (unsigned long long)f32_to_fp8(v0) << (8 * j);
        hi |= (unsigned long long)f32_to_fp8(v1) << (8 * j);
    }
    unsigned long long* dst = (unsigned long long*)(out + (size_t)p * 16);
    dst[0] = lo;
    dst[1] = hi;
}

#define MF(A_, B_, C_) (C_) = __builtin_amdgcn_mfma_scale_f32_32x32x64_f8f6f4( \
        (A_), (B_), (C_), 0, 0, 0, 0x7F7F7F7F, 0, 0x7F7F7F7F)

// LDS: [buf][sub-block (8)][ks (2)][2048]; frag at +lane*16 / +1024
#define AFRAG(BUF_, MI_, KS_) \
    ld8(Al + ((BUF_) << 15) + ((4 * g + (MI_)) << 12) + ((KS_) << 11) + (lane << 4))
#define BFRAG(BUF_, NI_, KS_) \
    ld8(Bl + ((BUF_) << 15) + ((2 * cc + (NI_)) << 12) + ((KS_) << 11) + (lane << 4))

// stage next pair's B / A strip for this wave (4 x async16, identity layout)
#define STAGEB(P_, NB_) do {                                                \
    const size_t go_ = (size_t)((P_) + 1) * 4096;                           \
    unsigned char* d_ = Bl + ((NB_) << 15) + (wid << 12);                   \
    async16(gBw + go_,        d_);        async16(gBw + go_ + 1024, d_ + 1024); \
    async16(gBw + go_ + 2048, d_ + 2048); async16(gBw + go_ + 3072, d_ + 3072); \
} while (0)
#define STAGEA(P_, NB_) do {                                                \
    const size_t go_ = (size_t)((P_) + 1) * 4096;                           \
    unsigned char* d_ = Al + ((NB_) << 15) + (wid << 12);                   \
    async16(gAw + go_,        d_);        async16(gAw + go_ + 1024, d_ + 1024); \
    async16(gAw + go_ + 2048, d_ + 2048); async16(gAw + go_ + 3072, d_ + 3072); \
} while (0)

// one phase: barrier-bounded MFMA cluster writing ONLY quadrant P_
// (m201 invariant: consecutive clusters touch disjoint acc registers)
#define MFQ_CORE(P_, A0_, A1_, BC_)                                         \
    __builtin_amdgcn_s_barrier();                                           \
    __builtin_amdgcn_s_setprio(1);                                          \
    MF(A0_, BC_[0], acc[P_][0]); MF(A0_, BC_[1], acc[P_][1]);               \
    MF(A1_, BC_[2], acc[P_][0]); MF(A1_, BC_[3], acc[P_][1]);               \
    __builtin_amdgcn_s_setprio(0);                                          \
    __builtin_amdgcn_s_barrier();

// one K-128 pair = 4 quadrant phases; tails carry staging + depth-1 A prefetch
// + next-pair B reads. vmcnt is placed BEFORE the phase barrier so the barrier
// proves ALL waves' stages landed (cross-wave RAW for global_load_lds).
#define PAIR(P_, CB_, NB_, BC_, BN_) do {                                   \
    MFQ_CORE(0, aP[0], aP[1], BC_)                                          \
    STAGEB(P_, NB_);                                                        \
    aQ[0] = AFRAG(CB_, 1, 0); aQ[1] = AFRAG(CB_, 1, 1);                     \
    MFQ_CORE(1, aQ[0], aQ[1], BC_)                                          \
    STAGEA(P_, NB_);                                                        \
    aP[0] = AFRAG(CB_, 2, 0); aP[1] = AFRAG(CB_, 2, 1);                     \
    asm volatile("s_waitcnt vmcnt(4)" ::: "memory");  /* B stages landed */ \
    MFQ_CORE(2, aP[0], aP[1], BC_)                                          \
    BN_[0] = AFRAGB0(NB_); BN_[1] = AFRAGB1(NB_);                           \
    aQ[0] = AFRAG(CB_, 3, 0); aQ[1] = AFRAG(CB_, 3, 1);                     \
    asm volatile("s_waitcnt vmcnt(0)" ::: "memory");  /* A stages landed */ \
    MFQ_CORE(3, aQ[0], aQ[1], BC_)                                          \
    BN_[2] = AFRAGB2(NB_); BN_[3] = AFRAGB3(NB_);                           \
    aP[0] = AFRAG(NB_, 0, 0); aP[1] = AFRAG(NB_, 0, 1);                     \
} while (0)

// helpers so PAIR stays readable: B frag order = [ks0ni0, ks0ni1, ks1ni0, ks1ni1]
#define AFRAGB0(B_) BFRAG(B_, 0, 0)
#define AFRAGB1(B_) BFRAG(B_, 1, 0)
#define AFRAGB2(B_) BFRAG(B_, 0, 1)
#define AFRAGB3(B_) BFRAG(B_, 1, 1)

#define PAIR_LAST(CB_, BC_) do {                                            \
    MFQ_CORE(0, aP[0], aP[1], BC_)                                          \
    aQ[0] = AFRAG(CB_, 1, 0); aQ[1] = AFRAG(CB_, 1, 1);                     \
    MFQ_CORE(1, aQ[0], aQ[1], BC_)                                          \
    aP[0] = AFRAG(CB_, 2, 0); aP[1] = AFRAG(CB_, 2, 1);                     \
    MFQ_CORE(2, aP[0], aP[1], BC_)                                          \
    aQ[0] = AFRAG(CB_, 3, 0); aQ[1] = AFRAG(CB_, 3, 1);                     \
    MFQ_CORE(3, aQ[0], aQ[1], BC_)                                          \
} while (0)

// ---- MX-fp8 GEMM: 256x256 tile, 8 waves (2Mx4N), 32x32x64 scaled MFMA ----
// m201-style quadrant-phase schedule. Scales e8m0 1.0 -> identical to fp8.
__global__ __launch_bounds__(512, 1) void gemm_fp8_kernel(
        const unsigned char* __restrict__ qA, const unsigned char* __restrict__ qB,
        const float* __restrict__ bias, float* __restrict__ out) {
    __shared__ unsigned char Al[2 * 32768];   // [buf][8 sb][2 ks][2048]
    __shared__ unsigned char Bl[2 * 32768];

    const int tid  = threadIdx.x;
    const int lane = tid & 63;
    const int wid  = tid >> 6;           // 0..7

    // XCD-aware swizzle: 1024 blocks % 8 == 0 -> bijective simple form
    const int cpx = gridDim.x >> 3;
    const int swz = (blockIdx.x & 7) * cpx + (blockIdx.x >> 3);
    const int bm = swz & 63;             // M/256 = 64 tiles
    const int bn = swz >> 6;             // N/256 = 16 tiles

    // staging strips: row-block stride = NSB*2048 = 64 KB
    const unsigned char* gAw = qA + ((size_t)(bm * 8 + wid) << 16) + (lane << 4);
    const unsigned char* gBw = qB + ((size_t)(bn * 8 + wid) << 16) + (lane << 4);

    // compute: wave (g = wid>>2, cc = wid&3) owns a 128x64 output sub-tile
    const int g  = wid >> 2;
    const int cc = wid & 3;

    floatx16 acc[4][2] = {};             // 4 quadrants x 2 col-blocks of 32x32
    intx8 aP[2], aQ[2], bX[4], bY[4];

    // ---- prologue: stage pair 0 into buf 0; read its B set + A quadrant 0 ----
    STAGEB(-1, 0);
    STAGEA(-1, 0);
    asm volatile("s_waitcnt vmcnt(0)" ::: "memory");
    __syncthreads();
    bX[0] = AFRAGB0(0); bX[1] = AFRAGB1(0); bX[2] = AFRAGB2(0); bX[3] = AFRAGB3(0);
    aP[0] = AFRAG(0, 0, 0); aP[1] = AFRAG(0, 0, 1);

    // ---- main: 16 pairs, LDS buffers and B reg-sets alternate per pair ----
    for (int r = 0; r < 7; ++r) {
        PAIR(2 * r,     0, 1, bX, bY);
        PAIR(2 * r + 1, 1, 0, bY, bX);
    }
    PAIR(14, 0, 1, bX, bY);
    PAIR_LAST(1, bY);

    // epilogue: 32x32 C/D layout col=lane&31, row=(r&3)+8*(r>>2)+4*(lane>>5)
    const int orow_b = bm * 256 + g * 128 + ((lane >> 5) << 2);
    const int ocol_b = bn * 256 + cc * 64 + (lane & 31);
#pragma unroll
    for (int ni = 0; ni < 2; ++ni) {
        const int oc = ocol_b + ni * 32;
        const float bv = bias[oc];
#pragma unroll
        for (int mi = 0; mi < 4; ++mi) {
#pragma unroll
            for (int r = 0; r < 16; ++r) {
                const int orow = orow_b + mi * 32 + (r & 3) + 8 * (r >> 2);
                out[(size_t)orow * N_DIM + oc] = fp8_roundtrip(acc[mi][ni][r]) + bv;
            }
        }
    }
}

// ---- fallback (only if ws too small): 1 thread per output, exact fp32 accumulation ----
__global__ void naive_kernel(const float* __restrict__ x, const float* __restrict__ w,
                             const float* __restrict__ bias, const float* __restrict__ sp,
                             float* __restrict__ out) {
    const int ncol = blockIdx.x * blockDim.x + threadIdx.x;
    const int m = blockIdx.y;
    const float s = *sp;
    float acc = 0.f;
    for (int k = 0; k < K_DIM; ++k) {
        float q = fp8_roundtrip(fminf(fmaxf(x[(size_t)m * K_DIM + k] * s, -0.5f), 0.5f));
        acc += q * w[(size_t)ncol * K_DIM + k];
    }
    out[(size_t)m * N_DIM + ncol] = fp8_roundtrip(acc) + bias[ncol];
}

extern "C" void kernel_launch(void* const* d_in, const int* in_sizes, int n_in,
                              void* d_out, int out_size, void* d_ws, size_t ws_size,
                              hipStream_t stream) {
    const float* x     = (const float*)d_in[0];
    const float* w     = (const float*)d_in[1];
    const float* bias  = (const float*)d_in[2];
    const float* scale = (const float*)d_in[3];
    float* out = (float*)d_out;

    const size_t needA = (size_t)M_DIM * K_DIM;   // 33.5 MB fp8
    const size_t needB = (size_t)N_DIM * K_DIM;   //  8.4 MB fp8

    if (ws_size >= needA + needB) {
        unsigned char* qA = (unsigned char*)d_ws;
        unsigned char* qB = qA + needA;
        quant_pack_kernel<<<(M_DIM * K_DIM / 16) / 256, 256, 0, stream>>>(x, qA, scale);
        quant_pack_kernel<<<(N_DIM * K_DIM / 16) / 256, 256, 0, stream>>>(w, qB, nullptr);
        gemm_fp8_kernel<<<(M_DIM / 256) * (N_DIM / 256), 512, 0, stream>>>(qA, qB, bias, out);
    } else {
        dim3 g(N_DIM / 256, M_DIM);
        naive_kernel<<<g, 256, 0, stream>>>(x, w, bias, scale, out);
    }
}